// Round 13
// baseline (509.062 us; speedup 1.0000x reference)
//
#include <hip/hip_runtime.h>
#include <hip/hip_bf16.h>

#define T_TOKENS 4096
#define HID 1024
#define FFN_ 4096
#define NE 8
#define MAXROWS 9216
#define MAXTILES 72
#define KSPLIT2 2

typedef unsigned short u16;
typedef __bf16 bf16x8 __attribute__((ext_vector_type(8)));
typedef float f32x4 __attribute__((ext_vector_type(4)));
typedef u16 u16x8 __attribute__((ext_vector_type(8)));

__device__ __forceinline__ u16 f2bf(float f) {
  __hip_bfloat16 h = __float2bfloat16(f);
  return *reinterpret_cast<u16*>(&h);
}

__device__ __forceinline__ void gload16(const void* g, void* l) {
  __builtin_amdgcn_global_load_lds(
      (const __attribute__((address_space(1))) void*)g,
      (__attribute__((address_space(3))) void*)l, 16, 0, 0);
}

// ---------------- router + x->bf16 convert (fused) ----------------
__global__ __launch_bounds__(256) void router_kernel(
    const float* __restrict__ x, const float* __restrict__ rw,
    int* __restrict__ sel, float* __restrict__ gsel, u16* __restrict__ xb) {
  int token = blockIdx.x * 4 + (threadIdx.x >> 6);
  int lane = threadIdx.x & 63;
  const float* xr = x + (size_t)token * HID;
  u16* xbr = xb + (size_t)token * HID;
  float acc[8];
#pragma unroll
  for (int e = 0; e < 8; e++) acc[e] = 0.f;
  for (int h = lane; h < HID; h += 64) {
    float xv = xr[h];
    xbr[h] = f2bf(xv);
    float4 r0 = *(const float4*)(rw + h * 8);
    float4 r1 = *(const float4*)(rw + h * 8 + 4);
    acc[0] += xv * r0.x; acc[1] += xv * r0.y; acc[2] += xv * r0.z; acc[3] += xv * r0.w;
    acc[4] += xv * r1.x; acc[5] += xv * r1.y; acc[6] += xv * r1.z; acc[7] += xv * r1.w;
  }
#pragma unroll
  for (int e = 0; e < 8; e++) {
#pragma unroll
    for (int o = 32; o > 0; o >>= 1) acc[e] += __shfl_down(acc[e], o);
  }
  if (lane == 0) {
    float mx = acc[0];
#pragma unroll
    for (int e = 1; e < 8; e++) mx = fmaxf(mx, acc[e]);
    float p[8], s = 0.f;
#pragma unroll
    for (int e = 0; e < 8; e++) { p[e] = expf(acc[e] - mx); s += p[e]; }
    float v0 = -1.f; int i0 = 0;
#pragma unroll
    for (int e = 0; e < 8; e++) if (p[e] > v0) { v0 = p[e]; i0 = e; }
    float v1 = -1.f; int i1 = 0;
#pragma unroll
    for (int e = 0; e < 8; e++) if (e != i0 && p[e] > v1) { v1 = p[e]; i1 = e; }
    float inv = 1.f / s;
    sel[token * 2] = i0;     gsel[token * 2] = v0 * inv;
    sel[token * 2 + 1] = i1; gsel[token * 2 + 1] = v1 * inv;
  }
}

// ---------------- hist + perm/grow default fill (fused) ----------------
__global__ __launch_bounds__(256) void hist_fill_kernel(
    const int* __restrict__ sel, int* __restrict__ counts,
    int* __restrict__ perm, float* __restrict__ grow) {
  __shared__ int lc[NE];
  if (threadIdx.x < NE) lc[threadIdx.x] = 0;
  __syncthreads();
  int gid = blockIdx.x * 256 + threadIdx.x;
  if (gid < T_TOKENS * 2) atomicAdd(&lc[sel[gid]], 1);
  if (gid < MAXROWS) { perm[gid] = -1; grow[gid] = 0.f; }
  __syncthreads();
  if (threadIdx.x < NE && lc[threadIdx.x] > 0)
    atomicAdd(&counts[threadIdx.x], lc[threadIdx.x]);
}

__global__ void base_kernel(const int* __restrict__ counts, int* __restrict__ cursor,
                            int* __restrict__ tilemap) {
  if (threadIdx.x == 0) {
    int base = 0;
    for (int e = 0; e < NE; e++) {
      cursor[e] = base;
      int padded = (base + counts[e] + 127) & ~127;
      for (int t = base >> 7; t < (padded >> 7); t++) tilemap[t] = e;
      base = padded;
    }
    for (int t = base >> 7; t < MAXTILES; t++) tilemap[t] = 0;
  }
}

__global__ __launch_bounds__(256) void scatter_kernel(
    const int* __restrict__ sel, const float* __restrict__ gsel,
    int* __restrict__ cursor, int* __restrict__ perm, float* __restrict__ grow) {
  int p = blockIdx.x * 256 + threadIdx.x;
  int e = sel[p];
  int pos = atomicAdd(&cursor[e], 1);
  perm[pos] = p >> 1;
  grow[pos] = gsel[p];
}

// ---------------- W1 [1024][32768] -> w1t [32768][1024] bf16 ----------------
__global__ __launch_bounds__(256) void transpose_w1(const float* __restrict__ w1, u16* __restrict__ w1t) {
  __shared__ float tile[64][65];
  int c0 = blockIdx.x * 64;
  int r0 = blockIdx.y * 64;
  int t = threadIdx.x;
  int ci = (t & 15) * 4;
  int ri = t >> 4;
#pragma unroll
  for (int rr = 0; rr < 64; rr += 16) {
    float4 v = *(const float4*)(w1 + (size_t)(r0 + ri + rr) * 32768 + c0 + ci);
    tile[ri + rr][ci] = v.x; tile[ri + rr][ci + 1] = v.y;
    tile[ri + rr][ci + 2] = v.z; tile[ri + rr][ci + 3] = v.w;
  }
  __syncthreads();
  int j = t >> 2;
  int q = t & 3;
  u16x8 o0, o1;
#pragma unroll
  for (int k = 0; k < 8; k++) o0[k] = f2bf(tile[q * 16 + k][j]);
#pragma unroll
  for (int k = 0; k < 8; k++) o1[k] = f2bf(tile[q * 16 + 8 + k][j]);
  u16* dst = w1t + (size_t)(c0 + j) * 1024 + r0 + q * 16;
  *(u16x8*)dst = o0;
  *(u16x8*)(dst + 8) = o1;
}

// ---------------- W2 [32768][1024] -> w2t [e][1024][4096] bf16 ----------------
__global__ __launch_bounds__(256) void transpose_w2(const float* __restrict__ w2, u16* __restrict__ w2t) {
  __shared__ float tile[64][65];
  int fb = blockIdx.x;
  int h0 = blockIdx.y * 64;
  int e = fb >> 6;
  int f0 = (fb & 63) * 64;
  int t = threadIdx.x;
  int ci = (t & 15) * 4;
  int ri = t >> 4;
#pragma unroll
  for (int rr = 0; rr < 64; rr += 16) {
    float4 v = *(const float4*)(w2 + (size_t)(fb * 64 + ri + rr) * 1024 + h0 + ci);
    tile[ri + rr][ci] = v.x; tile[ri + rr][ci + 1] = v.y;
    tile[ri + rr][ci + 2] = v.z; tile[ri + rr][ci + 3] = v.w;
  }
  __syncthreads();
  int j = t >> 2;
  int q = t & 3;
  u16x8 o0, o1;
#pragma unroll
  for (int k = 0; k < 8; k++) o0[k] = f2bf(tile[q * 16 + k][j]);
#pragma unroll
  for (int k = 0; k < 8; k++) o1[k] = f2bf(tile[q * 16 + 8 + k][j]);
  u16* dst = w2t + (size_t)e * 4194304 + (size_t)(h0 + j) * 4096 + f0 + q * 16;
  *(u16x8*)dst = o0;
  *(u16x8*)(dst + 8) = o1;
}

// ---------------- GEMM1: m97-style single-buffer, 32 KB LDS, 4-5 blocks/CU ----------------
__global__ __launch_bounds__(256, 4) void gemm1_kernel(
    const u16* __restrict__ xb, const u16* __restrict__ w1t,
    const int* __restrict__ perm, const float* __restrict__ grow,
    const int* __restrict__ tilemap, u16* __restrict__ hbuf,
    const u16* __restrict__ zp) {
  int bid = blockIdx.x;                 // 0..2303
  int pos = bid >> 3;                   // 0..287 within XCD chunk
  int nt = pos / 9;                     // 0..31 (slow)
  int mt = (bid & 7) * 9 + (pos - nt * 9);  // mt fastest
  int e = tilemap[mt];
  int row0 = mt * 128;
  int t = threadIdx.x, lane = t & 63, wave = t >> 6;
  __shared__ u16 As[128 * 64], Bs[128 * 64];   // 32 KB

  const u16* asrc[4]; int astep[4];
  const u16* bsrc[4];
#pragma unroll
  for (int i = 0; i < 4; i++) {
    int chunk = i * 256 + t, row = chunk >> 3, c = chunk & 7;
    int cs = c ^ (row & 7);
    int tok = perm[row0 + row];
    if (tok >= 0) { asrc[i] = xb + (size_t)tok * 1024 + cs * 8; astep[i] = 64; }
    else { asrc[i] = zp + cs * 8; astep[i] = 0; }
    bsrc[i] = w1t + (size_t)e * 4194304 + (size_t)(nt * 128 + row) * 1024 + cs * 8;
  }

  f32x4 acc[4][4] = {};
  int wm = (wave >> 1) * 64, wn = (wave & 1) * 64;
  int r = lane & 15, kg = lane >> 4;
  int X = (r & 7) << 4;
  int bA0 = wm * 128 + r * 128 + ((kg * 16) ^ X);
  int bA1 = wm * 128 + r * 128 + ((64 + kg * 16) ^ X);
  int bB0 = wn * 128 + r * 128 + ((kg * 16) ^ X);
  int bB1 = wn * 128 + r * 128 + ((64 + kg * 16) ^ X);

  for (int ks = 0; ks < 16; ks++) {
#pragma unroll
    for (int i = 0; i < 4; i++)
      gload16(asrc[i], (char*)As + i * 4096 + wave * 1024);
#pragma unroll
    for (int i = 0; i < 4; i++)
      gload16(bsrc[i], (char*)Bs + i * 4096 + wave * 1024);
#pragma unroll
    for (int i = 0; i < 4; i++) { asrc[i] += astep[i]; bsrc[i] += 64; }
    __syncthreads();
#pragma unroll
    for (int kk = 0; kk < 2; kk++) {
      int bA = kk ? bA1 : bA0;
      int bB = kk ? bB1 : bB0;
      bf16x8 af[4], bfr[4];
#pragma unroll
      for (int mi = 0; mi < 4; mi++)
        af[mi] = *(const bf16x8*)((const char*)As + bA + mi * 2048);
#pragma unroll
      for (int ni = 0; ni < 4; ni++)
        bfr[ni] = *(const bf16x8*)((const char*)Bs + bB + ni * 2048);
#pragma unroll
      for (int mi = 0; mi < 4; mi++)
#pragma unroll
        for (int ni = 0; ni < 4; ni++)
          acc[mi][ni] = __builtin_amdgcn_mfma_f32_16x16x32_bf16(af[mi], bfr[ni], acc[mi][ni], 0, 0, 0);
    }
    __syncthreads();
  }

  float g[4][4];
#pragma unroll
  for (int mi = 0; mi < 4; mi++)
#pragma unroll
    for (int j = 0; j < 4; j++)
      g[mi][j] = grow[row0 + wm + mi * 16 + kg * 4 + j];
#pragma unroll
  for (int mi = 0; mi < 4; mi++)
#pragma unroll
    for (int ni = 0; ni < 4; ni++)
#pragma unroll
      for (int j = 0; j < 4; j++) {
        int rl = wm + mi * 16 + kg * 4 + j;
        int col = nt * 128 + wn + ni * 16 + r;
        float v = acc[mi][ni][j];
        float ge = 0.5f * v * (1.0f + erff(v * 0.7071067811865475f)) * g[mi][j];
        hbuf[(size_t)(row0 + rl) * 4096 + col] = f2bf(ge);
      }
}

// ---------------- GEMM2: m97-style single-buffer, split-K=2, atomic combine ----------------
__global__ __launch_bounds__(256, 4) void gemm2_kernel(
    const u16* __restrict__ hbuf, const u16* __restrict__ w2t,
    const int* __restrict__ perm, const int* __restrict__ tilemap,
    float* __restrict__ out) {
  int bid = blockIdx.x;                  // 0..1151
  int pos = bid >> 3;                    // 0..143
  int rem = pos / 9;                     // 0..15 (slow): ks,nt
  int mt = (bid & 7) * 9 + (pos - rem * 9);  // mt fastest
  int ksplit = rem >> 3;                 // 0..1
  int nt = rem & 7;                      // 0..7
  int e = tilemap[mt];
  int row0 = mt * 128;
  int t = threadIdx.x, lane = t & 63, wave = t >> 6;
  __shared__ u16 As[128 * 64], Bs[128 * 64];

  const u16* asrc[4];
  const u16* bsrc[4];
#pragma unroll
  for (int i = 0; i < 4; i++) {
    int chunk = i * 256 + t, row = chunk >> 3, c = chunk & 7;
    int cs = c ^ (row & 7);
    asrc[i] = hbuf + (size_t)(row0 + row) * 4096 + (size_t)ksplit * 2048 + cs * 8;
    bsrc[i] = w2t + (size_t)e * 4194304 + (size_t)(nt * 128 + row) * 4096 + (size_t)ksplit * 2048 + cs * 8;
  }

  f32x4 acc[4][4] = {};
  int wm = (wave >> 1) * 64, wn = (wave & 1) * 64;
  int r = lane & 15, kg = lane >> 4;
  int X = (r & 7) << 4;
  int bA0 = wm * 128 + r * 128 + ((kg * 16) ^ X);
  int bA1 = wm * 128 + r * 128 + ((64 + kg * 16) ^ X);
  int bB0 = wn * 128 + r * 128 + ((kg * 16) ^ X);
  int bB1 = wn * 128 + r * 128 + ((64 + kg * 16) ^ X);

  for (int ks = 0; ks < 32; ks++) {
#pragma unroll
    for (int i = 0; i < 4; i++)
      gload16(asrc[i], (char*)As + i * 4096 + wave * 1024);
#pragma unroll
    for (int i = 0; i < 4; i++)
      gload16(bsrc[i], (char*)Bs + i * 4096 + wave * 1024);
#pragma unroll
    for (int i = 0; i < 4; i++) { asrc[i] += 64; bsrc[i] += 64; }
    __syncthreads();
#pragma unroll
    for (int kk = 0; kk < 2; kk++) {
      int bA = kk ? bA1 : bA0;
      int bB = kk ? bB1 : bB0;
      bf16x8 af[4], bfr[4];
#pragma unroll
      for (int mi = 0; mi < 4; mi++)
        af[mi] = *(const bf16x8*)((const char*)As + bA + mi * 2048);
#pragma unroll
      for (int ni = 0; ni < 4; ni++)
        bfr[ni] = *(const bf16x8*)((const char*)Bs + bB + ni * 2048);
#pragma unroll
      for (int mi = 0; mi < 4; mi++)
#pragma unroll
        for (int ni = 0; ni < 4; ni++)
          acc[mi][ni] = __builtin_amdgcn_mfma_f32_16x16x32_bf16(af[mi], bfr[ni], acc[mi][ni], 0, 0, 0);
    }
    __syncthreads();
  }

  int tok[4][4];
#pragma unroll
  for (int mi = 0; mi < 4; mi++)
#pragma unroll
    for (int j = 0; j < 4; j++)
      tok[mi][j] = perm[row0 + wm + mi * 16 + kg * 4 + j];
#pragma unroll
  for (int mi = 0; mi < 4; mi++)
#pragma unroll
    for (int ni = 0; ni < 4; ni++)
#pragma unroll
      for (int j = 0; j < 4; j++) {
        if (tok[mi][j] >= 0) {
          int col = nt * 128 + wn + ni * 16 + r;
          atomicAdd(out + (size_t)tok[mi][j] * 1024 + col, acc[mi][ni][j]);
        }
      }
}

extern "C" void kernel_launch(void* const* d_in, const int* in_sizes, int n_in,
                              void* d_out, int out_size, void* d_ws, size_t ws_size,
                              hipStream_t stream) {
  const float* x  = (const float*)d_in[0];
  const float* rw = (const float*)d_in[1];
  const float* w1 = (const float*)d_in[2];
  const float* w2 = (const float*)d_in[3];
  float* out = (float*)d_out;
  char* ws = (char*)d_ws;

  size_t off = 0;
  auto take = [&](size_t n) { char* p = ws + off; off += (n + 255) & ~255ull; return p; };
  u16* w1t   = (u16*)take(8ull * 4096 * 1024 * 2);
  u16* w2t   = (u16*)take(8ull * 4096 * 1024 * 2);
  u16* xb    = (u16*)take((size_t)T_TOKENS * HID * 2);
  u16* hbuf  = (u16*)take((size_t)MAXROWS * FFN_ * 2);
  int* sel   = (int*)take(T_TOKENS * 2 * 4);
  float* gsel = (float*)take(T_TOKENS * 2 * 4);
  int* perm  = (int*)take(MAXROWS * 4);
  float* grow = (float*)take(MAXROWS * 4);
  int* tmap  = (int*)take(MAXTILES * 4);
  int* counts = (int*)take(NE * 4);
  int* cursor = (int*)take(NE * 4);
  u16* zp    = (u16*)take(4096);

  hipMemsetAsync(zp, 0, 4096, stream);
  hipMemsetAsync(counts, 0, NE * 4, stream);
  hipMemsetAsync(out, 0, (size_t)T_TOKENS * HID * 4, stream);

  transpose_w1<<<dim3(512, 16), 256, 0, stream>>>(w1, w1t);
  transpose_w2<<<dim3(512, 16), 256, 0, stream>>>(w2, w2t);
  router_kernel<<<dim3(T_TOKENS / 4), 256, 0, stream>>>(x, rw, sel, gsel, xb);
  hist_fill_kernel<<<dim3(MAXROWS / 256), 256, 0, stream>>>(sel, counts, perm, grow);
  base_kernel<<<dim3(1), 64, 0, stream>>>(counts, cursor, tmap);
  scatter_kernel<<<dim3(T_TOKENS * 2 / 256), 256, 0, stream>>>(sel, gsel, cursor, perm, grow);
  gemm1_kernel<<<dim3(72 * 32), 256, 0, stream>>>(xb, w1t, perm, grow, tmap, hbuf, zp);
  gemm2_kernel<<<dim3(72 * 8 * KSPLIT2), 256, 0, stream>>>(hbuf, w2t, perm, tmap, out);
}

// Round 14
// 390.840 us; speedup vs baseline: 1.3025x; 1.3025x over previous
//
#include <hip/hip_runtime.h>
#include <hip/hip_bf16.h>

#define T_TOKENS 4096
#define HID 1024
#define FFN_ 4096
#define NE 8
#define MAXROWS 9216
#define MAXTILES 72
#define KSPLIT2 2

typedef unsigned short u16;
typedef __bf16 bf16x8 __attribute__((ext_vector_type(8)));
typedef float f32x4 __attribute__((ext_vector_type(4)));
typedef u16 u16x8 __attribute__((ext_vector_type(8)));

__device__ __forceinline__ u16 f2bf(float f) {
  __hip_bfloat16 h = __float2bfloat16(f);
  return *reinterpret_cast<u16*>(&h);
}

__device__ __forceinline__ void gload16(const void* g, void* l) {
  __builtin_amdgcn_global_load_lds(
      (const __attribute__((address_space(1))) void*)g,
      (__attribute__((address_space(3))) void*)l, 16, 0, 0);
}

#define WAIT_VM8() asm volatile("s_waitcnt vmcnt(8)" ::: "memory")
#define WAIT_VM0() asm volatile("s_waitcnt vmcnt(0)" ::: "memory")
#define BARRIER()  asm volatile("s_barrier" ::: "memory")

// ---------------- router + x->bf16 convert (fused) ----------------
__global__ __launch_bounds__(256) void router_kernel(
    const float* __restrict__ x, const float* __restrict__ rw,
    int* __restrict__ sel, float* __restrict__ gsel, u16* __restrict__ xb) {
  int token = blockIdx.x * 4 + (threadIdx.x >> 6);
  int lane = threadIdx.x & 63;
  const float* xr = x + (size_t)token * HID;
  u16* xbr = xb + (size_t)token * HID;
  float acc[8];
#pragma unroll
  for (int e = 0; e < 8; e++) acc[e] = 0.f;
  for (int h = lane; h < HID; h += 64) {
    float xv = xr[h];
    xbr[h] = f2bf(xv);
    float4 r0 = *(const float4*)(rw + h * 8);
    float4 r1 = *(const float4*)(rw + h * 8 + 4);
    acc[0] += xv * r0.x; acc[1] += xv * r0.y; acc[2] += xv * r0.z; acc[3] += xv * r0.w;
    acc[4] += xv * r1.x; acc[5] += xv * r1.y; acc[6] += xv * r1.z; acc[7] += xv * r1.w;
  }
#pragma unroll
  for (int e = 0; e < 8; e++) {
#pragma unroll
    for (int o = 32; o > 0; o >>= 1) acc[e] += __shfl_down(acc[e], o);
  }
  if (lane == 0) {
    float mx = acc[0];
#pragma unroll
    for (int e = 1; e < 8; e++) mx = fmaxf(mx, acc[e]);
    float p[8], s = 0.f;
#pragma unroll
    for (int e = 0; e < 8; e++) { p[e] = expf(acc[e] - mx); s += p[e]; }
    float v0 = -1.f; int i0 = 0;
#pragma unroll
    for (int e = 0; e < 8; e++) if (p[e] > v0) { v0 = p[e]; i0 = e; }
    float v1 = -1.f; int i1 = 0;
#pragma unroll
    for (int e = 0; e < 8; e++) if (e != i0 && p[e] > v1) { v1 = p[e]; i1 = e; }
    float inv = 1.f / s;
    sel[token * 2] = i0;     gsel[token * 2] = v0 * inv;
    sel[token * 2 + 1] = i1; gsel[token * 2 + 1] = v1 * inv;
  }
}

// ---------------- hist + perm/grow default fill (fused) ----------------
__global__ __launch_bounds__(256) void hist_fill_kernel(
    const int* __restrict__ sel, int* __restrict__ counts,
    int* __restrict__ perm, float* __restrict__ grow) {
  __shared__ int lc[NE];
  if (threadIdx.x < NE) lc[threadIdx.x] = 0;
  __syncthreads();
  int gid = blockIdx.x * 256 + threadIdx.x;
  if (gid < T_TOKENS * 2) atomicAdd(&lc[sel[gid]], 1);
  if (gid < MAXROWS) { perm[gid] = -1; grow[gid] = 0.f; }
  __syncthreads();
  if (threadIdx.x < NE && lc[threadIdx.x] > 0)
    atomicAdd(&counts[threadIdx.x], lc[threadIdx.x]);
}

__global__ void base_kernel(const int* __restrict__ counts, int* __restrict__ cursor,
                            int* __restrict__ tilemap) {
  if (threadIdx.x == 0) {
    int base = 0;
    for (int e = 0; e < NE; e++) {
      cursor[e] = base;
      int padded = (base + counts[e] + 127) & ~127;
      for (int t = base >> 7; t < (padded >> 7); t++) tilemap[t] = e;
      base = padded;
    }
    for (int t = base >> 7; t < MAXTILES; t++) tilemap[t] = 0;
  }
}

__global__ __launch_bounds__(256) void scatter_kernel(
    const int* __restrict__ sel, const float* __restrict__ gsel,
    int* __restrict__ cursor, int* __restrict__ perm, float* __restrict__ grow) {
  int p = blockIdx.x * 256 + threadIdx.x;
  int e = sel[p];
  int pos = atomicAdd(&cursor[e], 1);
  perm[pos] = p >> 1;
  grow[pos] = gsel[p];
}

// ---------------- fused weight transpose: W1 and W2 in one launch ----------------
// blocks [0,8192): W1 [1024][32768] -> w1t [32768][1024] bf16
// blocks [8192,16384): W2 [32768][1024] -> w2t [e][1024][4096] bf16
__global__ __launch_bounds__(256) void transpose_weights(
    const float* __restrict__ w1, u16* __restrict__ w1t,
    const float* __restrict__ w2, u16* __restrict__ w2t) {
  __shared__ float tile[64][65];
  int id = blockIdx.x;
  int t = threadIdx.x;
  int ci = (t & 15) * 4;
  int ri = t >> 4;
  int j = t >> 2;
  int q = t & 3;
  if (id < 8192) {
    int c0 = (id & 511) * 64;
    int r0 = (id >> 9) * 64;
#pragma unroll
    for (int rr = 0; rr < 64; rr += 16) {
      float4 v = *(const float4*)(w1 + (size_t)(r0 + ri + rr) * 32768 + c0 + ci);
      tile[ri + rr][ci] = v.x; tile[ri + rr][ci + 1] = v.y;
      tile[ri + rr][ci + 2] = v.z; tile[ri + rr][ci + 3] = v.w;
    }
    __syncthreads();
    u16x8 o0, o1;
#pragma unroll
    for (int k = 0; k < 8; k++) o0[k] = f2bf(tile[q * 16 + k][j]);
#pragma unroll
    for (int k = 0; k < 8; k++) o1[k] = f2bf(tile[q * 16 + 8 + k][j]);
    u16* dst = w1t + (size_t)(c0 + j) * 1024 + r0 + q * 16;
    *(u16x8*)dst = o0;
    *(u16x8*)(dst + 8) = o1;
  } else {
    id -= 8192;
    int fb = id & 511;
    int h0 = (id >> 9) * 64;
    int e = fb >> 6;
    int f0 = (fb & 63) * 64;
#pragma unroll
    for (int rr = 0; rr < 64; rr += 16) {
      float4 v = *(const float4*)(w2 + (size_t)(fb * 64 + ri + rr) * 1024 + h0 + ci);
      tile[ri + rr][ci] = v.x; tile[ri + rr][ci + 1] = v.y;
      tile[ri + rr][ci + 2] = v.z; tile[ri + rr][ci + 3] = v.w;
    }
    __syncthreads();
    u16x8 o0, o1;
#pragma unroll
    for (int k = 0; k < 8; k++) o0[k] = f2bf(tile[q * 16 + k][j]);
#pragma unroll
    for (int k = 0; k < 8; k++) o1[k] = f2bf(tile[q * 16 + 8 + k][j]);
    u16* dst = w2t + (size_t)e * 4194304 + (size_t)(h0 + j) * 4096 + f0 + q * 16;
    *(u16x8*)dst = o0;
    *(u16x8*)(dst + 8) = o1;
  }
}

// ---------------- GEMM1: H = gate * gelu(Xg @ W1e), bf16 out ----------------
// R9 structure: counted vmcnt(8) 2-deep dbuf, XCD chunk mt-fastest, hoisted LDS bases.
__global__ __launch_bounds__(256) void gemm1_kernel(
    const u16* __restrict__ xb, const u16* __restrict__ w1t,
    const int* __restrict__ perm, const float* __restrict__ grow,
    const int* __restrict__ tilemap, u16* __restrict__ hbuf,
    const u16* __restrict__ zp) {
  int bid = blockIdx.x;                 // 0..2303
  int pos = bid >> 3;                   // 0..287 within XCD chunk
  int nt = pos / 9;                     // 0..31 (slow)
  int mt = (bid & 7) * 9 + (pos - nt * 9);  // mt fastest
  int e = tilemap[mt];
  int row0 = mt * 128;
  int t = threadIdx.x, lane = t & 63, wave = t >> 6;
  __shared__ u16 As[2][128 * 64], Bs[2][128 * 64];

  const u16* asrc[4]; int astep[4];
  const u16* bsrc[4];
#pragma unroll
  for (int i = 0; i < 4; i++) {
    int chunk = i * 256 + t, row = chunk >> 3, c = chunk & 7;
    int cs = c ^ (row & 7);
    int tok = perm[row0 + row];
    if (tok >= 0) { asrc[i] = xb + (size_t)tok * 1024 + cs * 8; astep[i] = 64; }
    else { asrc[i] = zp + cs * 8; astep[i] = 0; }
    bsrc[i] = w1t + (size_t)e * 4194304 + (size_t)(nt * 128 + row) * 1024 + cs * 8;
  }

  f32x4 acc[4][4] = {};
  int wm = (wave >> 1) * 64, wn = (wave & 1) * 64;
  int r = lane & 15, kg = lane >> 4;
  int X = (r & 7) << 4;
  int bA0 = wm * 128 + r * 128 + ((kg * 16) ^ X);
  int bA1 = wm * 128 + r * 128 + ((64 + kg * 16) ^ X);
  int bB0 = wn * 128 + r * 128 + ((kg * 16) ^ X);
  int bB1 = wn * 128 + r * 128 + ((64 + kg * 16) ^ X);

  auto stage = [&](int p) {
#pragma unroll
    for (int i = 0; i < 4; i++)
      gload16(asrc[i], (char*)&As[p][0] + i * 4096 + wave * 1024);
#pragma unroll
    for (int i = 0; i < 4; i++)
      gload16(bsrc[i], (char*)&Bs[p][0] + i * 4096 + wave * 1024);
#pragma unroll
    for (int i = 0; i < 4; i++) { asrc[i] += astep[i]; bsrc[i] += 64; }
  };
  auto compute = [&](int p) {
    const char* Ab = (const char*)&As[p][0];
    const char* Bb = (const char*)&Bs[p][0];
#pragma unroll
    for (int kk = 0; kk < 2; kk++) {
      int bA = kk ? bA1 : bA0;
      int bB = kk ? bB1 : bB0;
      bf16x8 af[4], bfr[4];
#pragma unroll
      for (int mi = 0; mi < 4; mi++)
        af[mi] = *(const bf16x8*)(Ab + bA + mi * 2048);
#pragma unroll
      for (int ni = 0; ni < 4; ni++)
        bfr[ni] = *(const bf16x8*)(Bb + bB + ni * 2048);
#pragma unroll
      for (int mi = 0; mi < 4; mi++)
#pragma unroll
        for (int ni = 0; ni < 4; ni++)
          acc[mi][ni] = __builtin_amdgcn_mfma_f32_16x16x32_bf16(af[mi], bfr[ni], acc[mi][ni], 0, 0, 0);
    }
  };

  stage(0);
  stage(1);
  for (int ks = 0; ks < 15; ks++) {
    WAIT_VM8();
    BARRIER();
    compute(ks & 1);
    BARRIER();
    if (ks < 14) stage(ks & 1);
  }
  WAIT_VM0();
  BARRIER();
  compute(1);

  float g[4][4];
#pragma unroll
  for (int mi = 0; mi < 4; mi++)
#pragma unroll
    for (int j = 0; j < 4; j++)
      g[mi][j] = grow[row0 + wm + mi * 16 + kg * 4 + j];
#pragma unroll
  for (int mi = 0; mi < 4; mi++)
#pragma unroll
    for (int ni = 0; ni < 4; ni++)
#pragma unroll
      for (int j = 0; j < 4; j++) {
        int rl = wm + mi * 16 + kg * 4 + j;
        int col = nt * 128 + wn + ni * 16 + r;
        float v = acc[mi][ni][j];
        float ge = 0.5f * v * (1.0f + erff(v * 0.7071067811865475f)) * g[mi][j];
        hbuf[(size_t)(row0 + rl) * 4096 + col] = f2bf(ge);
      }
}

// ---------------- GEMM2: out[tok] += H @ W2e (split-K=2, atomic combine) ----------------
__global__ __launch_bounds__(256) void gemm2_kernel(
    const u16* __restrict__ hbuf, const u16* __restrict__ w2t,
    const int* __restrict__ perm, const int* __restrict__ tilemap,
    float* __restrict__ out) {
  int bid = blockIdx.x;                  // 0..1151
  int pos = bid >> 3;                    // 0..143
  int rem = pos / 9;                     // 0..15 (slow): ks,nt
  int mt = (bid & 7) * 9 + (pos - rem * 9);  // mt fastest
  int ksplit = rem >> 3;                 // 0..1
  int nt = rem & 7;                      // 0..7
  int e = tilemap[mt];
  int row0 = mt * 128;
  int t = threadIdx.x, lane = t & 63, wave = t >> 6;
  __shared__ u16 As[2][128 * 64], Bs[2][128 * 64];

  const u16* asrc[4];
  const u16* bsrc[4];
#pragma unroll
  for (int i = 0; i < 4; i++) {
    int chunk = i * 256 + t, row = chunk >> 3, c = chunk & 7;
    int cs = c ^ (row & 7);
    asrc[i] = hbuf + (size_t)(row0 + row) * 4096 + (size_t)ksplit * 2048 + cs * 8;
    bsrc[i] = w2t + (size_t)e * 4194304 + (size_t)(nt * 128 + row) * 4096 + (size_t)ksplit * 2048 + cs * 8;
  }

  f32x4 acc[4][4] = {};
  int wm = (wave >> 1) * 64, wn = (wave & 1) * 64;
  int r = lane & 15, kg = lane >> 4;
  int X = (r & 7) << 4;
  int bA0 = wm * 128 + r * 128 + ((kg * 16) ^ X);
  int bA1 = wm * 128 + r * 128 + ((64 + kg * 16) ^ X);
  int bB0 = wn * 128 + r * 128 + ((kg * 16) ^ X);
  int bB1 = wn * 128 + r * 128 + ((64 + kg * 16) ^ X);

  auto stage = [&](int p) {
#pragma unroll
    for (int i = 0; i < 4; i++)
      gload16(asrc[i], (char*)&As[p][0] + i * 4096 + wave * 1024);
#pragma unroll
    for (int i = 0; i < 4; i++)
      gload16(bsrc[i], (char*)&Bs[p][0] + i * 4096 + wave * 1024);
#pragma unroll
    for (int i = 0; i < 4; i++) { asrc[i] += 64; bsrc[i] += 64; }
  };
  auto compute = [&](int p) {
    const char* Ab = (const char*)&As[p][0];
    const char* Bb = (const char*)&Bs[p][0];
#pragma unroll
    for (int kk = 0; kk < 2; kk++) {
      int bA = kk ? bA1 : bA0;
      int bB = kk ? bB1 : bB0;
      bf16x8 af[4], bfr[4];
#pragma unroll
      for (int mi = 0; mi < 4; mi++)
        af[mi] = *(const bf16x8*)(Ab + bA + mi * 2048);
#pragma unroll
      for (int ni = 0; ni < 4; ni++)
        bfr[ni] = *(const bf16x8*)(Bb + bB + ni * 2048);
#pragma unroll
      for (int mi = 0; mi < 4; mi++)
#pragma unroll
        for (int ni = 0; ni < 4; ni++)
          acc[mi][ni] = __builtin_amdgcn_mfma_f32_16x16x32_bf16(af[mi], bfr[ni], acc[mi][ni], 0, 0, 0);
    }
  };

  stage(0);
  stage(1);
  for (int ks = 0; ks < 31; ks++) {
    WAIT_VM8();
    BARRIER();
    compute(ks & 1);
    BARRIER();
    if (ks < 30) stage(ks & 1);
  }
  WAIT_VM0();
  BARRIER();
  compute(1);

  int tok[4][4];
#pragma unroll
  for (int mi = 0; mi < 4; mi++)
#pragma unroll
    for (int j = 0; j < 4; j++)
      tok[mi][j] = perm[row0 + wm + mi * 16 + kg * 4 + j];
#pragma unroll
  for (int mi = 0; mi < 4; mi++)
#pragma unroll
    for (int ni = 0; ni < 4; ni++)
#pragma unroll
      for (int j = 0; j < 4; j++) {
        if (tok[mi][j] >= 0) {
          int col = nt * 128 + wn + ni * 16 + r;
          atomicAdd(out + (size_t)tok[mi][j] * 1024 + col, acc[mi][ni][j]);
        }
      }
}

extern "C" void kernel_launch(void* const* d_in, const int* in_sizes, int n_in,
                              void* d_out, int out_size, void* d_ws, size_t ws_size,
                              hipStream_t stream) {
  const float* x  = (const float*)d_in[0];
  const float* rw = (const float*)d_in[1];
  const float* w1 = (const float*)d_in[2];
  const float* w2 = (const float*)d_in[3];
  float* out = (float*)d_out;
  char* ws = (char*)d_ws;

  size_t off = 0;
  auto take = [&](size_t n) { char* p = ws + off; off += (n + 255) & ~255ull; return p; };
  u16* w1t   = (u16*)take(8ull * 4096 * 1024 * 2);
  u16* w2t   = (u16*)take(8ull * 4096 * 1024 * 2);
  u16* xb    = (u16*)take((size_t)T_TOKENS * HID * 2);
  u16* hbuf  = (u16*)take((size_t)MAXROWS * FFN_ * 2);
  int* sel   = (int*)take(T_TOKENS * 2 * 4);
  float* gsel = (float*)take(T_TOKENS * 2 * 4);
  int* perm  = (int*)take(MAXROWS * 4);
  float* grow = (float*)take(MAXROWS * 4);
  int* tmap  = (int*)take(MAXTILES * 4);
  int* counts = (int*)take(NE * 4);
  int* cursor = (int*)take(NE * 4);
  u16* zp    = (u16*)take(4096);

  hipMemsetAsync(zp, 0, 4096, stream);
  hipMemsetAsync(counts, 0, NE * 4, stream);
  hipMemsetAsync(out, 0, (size_t)T_TOKENS * HID * 4, stream);

  transpose_weights<<<dim3(16384), 256, 0, stream>>>(w1, w1t, w2, w2t);
  router_kernel<<<dim3(T_TOKENS / 4), 256, 0, stream>>>(x, rw, sel, gsel, xb);
  hist_fill_kernel<<<dim3(MAXROWS / 256), 256, 0, stream>>>(sel, counts, perm, grow);
  base_kernel<<<dim3(1), 64, 0, stream>>>(counts, cursor, tmap);
  scatter_kernel<<<dim3(T_TOKENS * 2 / 256), 256, 0, stream>>>(sel, gsel, cursor, perm, grow);
  gemm1_kernel<<<dim3(72 * 32), 256, 0, stream>>>(xb, w1t, perm, grow, tmap, hbuf, zp);
  gemm2_kernel<<<dim3(72 * 8 * KSPLIT2), 256, 0, stream>>>(hbuf, w2t, perm, tmap, out);
}

// Round 15
// 387.050 us; speedup vs baseline: 1.3152x; 1.0098x over previous
//
#include <hip/hip_runtime.h>
#include <hip/hip_bf16.h>

#define T_TOKENS 4096
#define HID 1024
#define FFN_ 4096
#define NE 8
#define MAXROWS 9216
#define MAXTILES 72
#define KSPLIT2 2

typedef unsigned short u16;
typedef __bf16 bf16x8 __attribute__((ext_vector_type(8)));
typedef float f32x4 __attribute__((ext_vector_type(4)));
typedef u16 u16x8 __attribute__((ext_vector_type(8)));

__device__ __forceinline__ u16 f2bf(float f) {
  __hip_bfloat16 h = __float2bfloat16(f);
  return *reinterpret_cast<u16*>(&h);
}

__device__ __forceinline__ void gload16(const void* g, void* l) {
  __builtin_amdgcn_global_load_lds(
      (const __attribute__((address_space(1))) void*)g,
      (__attribute__((address_space(3))) void*)l, 16, 0, 0);
}

#define WAIT_VM8() asm volatile("s_waitcnt vmcnt(8)" ::: "memory")
#define WAIT_VM0() asm volatile("s_waitcnt vmcnt(0)" ::: "memory")
#define BARRIER()  asm volatile("s_barrier" ::: "memory")

// ---------------- router + x->bf16 convert (fused) + scratch zeroing ----------------
__global__ __launch_bounds__(256) void router_kernel(
    const float* __restrict__ x, const float* __restrict__ rw,
    int* __restrict__ sel, float* __restrict__ gsel, u16* __restrict__ xb,
    int* __restrict__ counts, int* __restrict__ done, u16* __restrict__ zp) {
  if (blockIdx.x == 0) {
    // zero counts(8), done(1), zp(2048 u16) — consumed by later launches
    if (threadIdx.x < NE) counts[threadIdx.x] = 0;
    if (threadIdx.x == NE) *done = 0;
    *(u16x8*)(zp + threadIdx.x * 8) = (u16x8){0, 0, 0, 0, 0, 0, 0, 0};
  }
  int token = blockIdx.x * 4 + (threadIdx.x >> 6);
  int lane = threadIdx.x & 63;
  const float* xr = x + (size_t)token * HID;
  u16* xbr = xb + (size_t)token * HID;
  float acc[8];
#pragma unroll
  for (int e = 0; e < 8; e++) acc[e] = 0.f;
  for (int h = lane; h < HID; h += 64) {
    float xv = xr[h];
    xbr[h] = f2bf(xv);
    float4 r0 = *(const float4*)(rw + h * 8);
    float4 r1 = *(const float4*)(rw + h * 8 + 4);
    acc[0] += xv * r0.x; acc[1] += xv * r0.y; acc[2] += xv * r0.z; acc[3] += xv * r0.w;
    acc[4] += xv * r1.x; acc[5] += xv * r1.y; acc[6] += xv * r1.z; acc[7] += xv * r1.w;
  }
#pragma unroll
  for (int e = 0; e < 8; e++) {
#pragma unroll
    for (int o = 32; o > 0; o >>= 1) acc[e] += __shfl_down(acc[e], o);
  }
  if (lane == 0) {
    float mx = acc[0];
#pragma unroll
    for (int e = 1; e < 8; e++) mx = fmaxf(mx, acc[e]);
    float p[8], s = 0.f;
#pragma unroll
    for (int e = 0; e < 8; e++) { p[e] = expf(acc[e] - mx); s += p[e]; }
    float v0 = -1.f; int i0 = 0;
#pragma unroll
    for (int e = 0; e < 8; e++) if (p[e] > v0) { v0 = p[e]; i0 = e; }
    float v1 = -1.f; int i1 = 0;
#pragma unroll
    for (int e = 0; e < 8; e++) if (e != i0 && p[e] > v1) { v1 = p[e]; i1 = e; }
    float inv = 1.f / s;
    sel[token * 2] = i0;     gsel[token * 2] = v0 * inv;
    sel[token * 2 + 1] = i1; gsel[token * 2 + 1] = v1 * inv;
  }
}

// ---------------- hist + fill + (last block) bases/tilemap ----------------
__global__ __launch_bounds__(256) void hist_fill_kernel(
    const int* __restrict__ sel, int* __restrict__ counts,
    int* __restrict__ perm, float* __restrict__ grow,
    int* __restrict__ done, int* __restrict__ cursor, int* __restrict__ tilemap) {
  __shared__ int lc[NE];
  if (threadIdx.x < NE) lc[threadIdx.x] = 0;
  __syncthreads();
  int gid = blockIdx.x * 256 + threadIdx.x;
  if (gid < T_TOKENS * 2) atomicAdd(&lc[sel[gid]], 1);
  if (gid < MAXROWS) { perm[gid] = -1; grow[gid] = 0.f; }
  __syncthreads();
  if (threadIdx.x < NE && lc[threadIdx.x] > 0)
    atomicAdd(&counts[threadIdx.x], lc[threadIdx.x]);
  if (threadIdx.x == 0) {
    __threadfence();
    int prev = atomicAdd(done, 1);
    if (prev == (int)gridDim.x - 1) {   // last block: compute bases + tilemap
      int base = 0;
      for (int e = 0; e < NE; e++) {
        cursor[e] = base;
        int cnt = atomicAdd(&counts[e], 0);
        int padded = (base + cnt + 127) & ~127;
        for (int t2 = base >> 7; t2 < (padded >> 7); t2++) tilemap[t2] = e;
        base = padded;
      }
      for (int t2 = base >> 7; t2 < MAXTILES; t2++) tilemap[t2] = -1;  // unused
    }
  }
}

__global__ __launch_bounds__(256) void scatter_kernel(
    const int* __restrict__ sel, const float* __restrict__ gsel,
    int* __restrict__ cursor, int* __restrict__ perm, float* __restrict__ grow) {
  int p = blockIdx.x * 256 + threadIdx.x;
  int e = sel[p];
  int pos = atomicAdd(&cursor[e], 1);
  perm[pos] = p >> 1;
  grow[pos] = gsel[p];
}

// ---------------- fused weight transpose: W1 and W2 in one launch ----------------
__global__ __launch_bounds__(256) void transpose_weights(
    const float* __restrict__ w1, u16* __restrict__ w1t,
    const float* __restrict__ w2, u16* __restrict__ w2t) {
  __shared__ float tile[64][65];
  int id = blockIdx.x;
  int t = threadIdx.x;
  int ci = (t & 15) * 4;
  int ri = t >> 4;
  int j = t >> 2;
  int q = t & 3;
  if (id < 8192) {
    int c0 = (id & 511) * 64;
    int r0 = (id >> 9) * 64;
#pragma unroll
    for (int rr = 0; rr < 64; rr += 16) {
      float4 v = *(const float4*)(w1 + (size_t)(r0 + ri + rr) * 32768 + c0 + ci);
      tile[ri + rr][ci] = v.x; tile[ri + rr][ci + 1] = v.y;
      tile[ri + rr][ci + 2] = v.z; tile[ri + rr][ci + 3] = v.w;
    }
    __syncthreads();
    u16x8 o0, o1;
#pragma unroll
    for (int k = 0; k < 8; k++) o0[k] = f2bf(tile[q * 16 + k][j]);
#pragma unroll
    for (int k = 0; k < 8; k++) o1[k] = f2bf(tile[q * 16 + 8 + k][j]);
    u16* dst = w1t + (size_t)(c0 + j) * 1024 + r0 + q * 16;
    *(u16x8*)dst = o0;
    *(u16x8*)(dst + 8) = o1;
  } else {
    id -= 8192;
    int fb = id & 511;
    int h0 = (id >> 9) * 64;
    int e = fb >> 6;
    int f0 = (fb & 63) * 64;
#pragma unroll
    for (int rr = 0; rr < 64; rr += 16) {
      float4 v = *(const float4*)(w2 + (size_t)(fb * 64 + ri + rr) * 1024 + h0 + ci);
      tile[ri + rr][ci] = v.x; tile[ri + rr][ci + 1] = v.y;
      tile[ri + rr][ci + 2] = v.z; tile[ri + rr][ci + 3] = v.w;
    }
    __syncthreads();
    u16x8 o0, o1;
#pragma unroll
    for (int k = 0; k < 8; k++) o0[k] = f2bf(tile[q * 16 + k][j]);
#pragma unroll
    for (int k = 0; k < 8; k++) o1[k] = f2bf(tile[q * 16 + 8 + k][j]);
    u16* dst = w2t + (size_t)e * 4194304 + (size_t)(h0 + j) * 4096 + f0 + q * 16;
    *(u16x8*)dst = o0;
    *(u16x8*)(dst + 8) = o1;
  }
}

// ---------------- GEMM1: H = gate * gelu(Xg @ W1e), bf16 out ----------------
// R9 structure: counted vmcnt(8) 2-deep dbuf, XCD chunk mt-fastest, hoisted LDS bases.
__global__ __launch_bounds__(256) void gemm1_kernel(
    const u16* __restrict__ xb, const u16* __restrict__ w1t,
    const int* __restrict__ perm, const float* __restrict__ grow,
    const int* __restrict__ tilemap, u16* __restrict__ hbuf,
    const u16* __restrict__ zp) {
  int bid = blockIdx.x;                 // 0..2303
  int pos = bid >> 3;                   // 0..287 within XCD chunk
  int nt = pos / 9;                     // 0..31 (slow)
  int mt = (bid & 7) * 9 + (pos - nt * 9);  // mt fastest
  int e = tilemap[mt];
  if (e < 0) return;                    // unused tile: no work, never read downstream
  int row0 = mt * 128;
  int t = threadIdx.x, lane = t & 63, wave = t >> 6;
  __shared__ u16 As[2][128 * 64], Bs[2][128 * 64];

  const u16* asrc[4]; int astep[4];
  const u16* bsrc[4];
#pragma unroll
  for (int i = 0; i < 4; i++) {
    int chunk = i * 256 + t, row = chunk >> 3, c = chunk & 7;
    int cs = c ^ (row & 7);
    int tok = perm[row0 + row];
    if (tok >= 0) { asrc[i] = xb + (size_t)tok * 1024 + cs * 8; astep[i] = 64; }
    else { asrc[i] = zp + cs * 8; astep[i] = 0; }
    bsrc[i] = w1t + (size_t)e * 4194304 + (size_t)(nt * 128 + row) * 1024 + cs * 8;
  }

  f32x4 acc[4][4] = {};
  int wm = (wave >> 1) * 64, wn = (wave & 1) * 64;
  int r = lane & 15, kg = lane >> 4;
  int X = (r & 7) << 4;
  int bA0 = wm * 128 + r * 128 + ((kg * 16) ^ X);
  int bA1 = wm * 128 + r * 128 + ((64 + kg * 16) ^ X);
  int bB0 = wn * 128 + r * 128 + ((kg * 16) ^ X);
  int bB1 = wn * 128 + r * 128 + ((64 + kg * 16) ^ X);

  auto stage = [&](int p) {
#pragma unroll
    for (int i = 0; i < 4; i++)
      gload16(asrc[i], (char*)&As[p][0] + i * 4096 + wave * 1024);
#pragma unroll
    for (int i = 0; i < 4; i++)
      gload16(bsrc[i], (char*)&Bs[p][0] + i * 4096 + wave * 1024);
#pragma unroll
    for (int i = 0; i < 4; i++) { asrc[i] += astep[i]; bsrc[i] += 64; }
  };
  auto compute = [&](int p) {
    const char* Ab = (const char*)&As[p][0];
    const char* Bb = (const char*)&Bs[p][0];
#pragma unroll
    for (int kk = 0; kk < 2; kk++) {
      int bA = kk ? bA1 : bA0;
      int bB = kk ? bB1 : bB0;
      bf16x8 af[4], bfr[4];
#pragma unroll
      for (int mi = 0; mi < 4; mi++)
        af[mi] = *(const bf16x8*)(Ab + bA + mi * 2048);
#pragma unroll
      for (int ni = 0; ni < 4; ni++)
        bfr[ni] = *(const bf16x8*)(Bb + bB + ni * 2048);
#pragma unroll
      for (int mi = 0; mi < 4; mi++)
#pragma unroll
        for (int ni = 0; ni < 4; ni++)
          acc[mi][ni] = __builtin_amdgcn_mfma_f32_16x16x32_bf16(af[mi], bfr[ni], acc[mi][ni], 0, 0, 0);
    }
  };

  stage(0);
  stage(1);
  for (int ks = 0; ks < 15; ks++) {
    WAIT_VM8();
    BARRIER();
    compute(ks & 1);
    BARRIER();
    if (ks < 14) stage(ks & 1);
  }
  WAIT_VM0();
  BARRIER();
  compute(1);

  float g[4][4];
#pragma unroll
  for (int mi = 0; mi < 4; mi++)
#pragma unroll
    for (int j = 0; j < 4; j++)
      g[mi][j] = grow[row0 + wm + mi * 16 + kg * 4 + j];
#pragma unroll
  for (int mi = 0; mi < 4; mi++)
#pragma unroll
    for (int ni = 0; ni < 4; ni++)
#pragma unroll
      for (int j = 0; j < 4; j++) {
        int rl = wm + mi * 16 + kg * 4 + j;
        int col = nt * 128 + wn + ni * 16 + r;
        float v = acc[mi][ni][j];
        float ge = 0.5f * v * (1.0f + erff(v * 0.7071067811865475f)) * g[mi][j];
        hbuf[(size_t)(row0 + rl) * 4096 + col] = f2bf(ge);
      }
}

// ---------------- GEMM2: out[tok] += H @ W2e (split-K=2, atomic combine) ----------------
__global__ __launch_bounds__(256) void gemm2_kernel(
    const u16* __restrict__ hbuf, const u16* __restrict__ w2t,
    const int* __restrict__ perm, const int* __restrict__ tilemap,
    float* __restrict__ out) {
  int bid = blockIdx.x;                  // 0..1151
  int pos = bid >> 3;                    // 0..143
  int rem = pos / 9;                     // 0..15 (slow): ks,nt
  int mt = (bid & 7) * 9 + (pos - rem * 9);  // mt fastest
  int e = tilemap[mt];
  if (e < 0) return;                     // matches gemm1's skipped tiles
  int ksplit = rem >> 3;                 // 0..1
  int nt = rem & 7;                      // 0..7
  int row0 = mt * 128;
  int t = threadIdx.x, lane = t & 63, wave = t >> 6;
  __shared__ u16 As[2][128 * 64], Bs[2][128 * 64];

  const u16* asrc[4];
  const u16* bsrc[4];
#pragma unroll
  for (int i = 0; i < 4; i++) {
    int chunk = i * 256 + t, row = chunk >> 3, c = chunk & 7;
    int cs = c ^ (row & 7);
    asrc[i] = hbuf + (size_t)(row0 + row) * 4096 + (size_t)ksplit * 2048 + cs * 8;
    bsrc[i] = w2t + (size_t)e * 4194304 + (size_t)(nt * 128 + row) * 4096 + (size_t)ksplit * 2048 + cs * 8;
  }

  f32x4 acc[4][4] = {};
  int wm = (wave >> 1) * 64, wn = (wave & 1) * 64;
  int r = lane & 15, kg = lane >> 4;
  int X = (r & 7) << 4;
  int bA0 = wm * 128 + r * 128 + ((kg * 16) ^ X);
  int bA1 = wm * 128 + r * 128 + ((64 + kg * 16) ^ X);
  int bB0 = wn * 128 + r * 128 + ((kg * 16) ^ X);
  int bB1 = wn * 128 + r * 128 + ((64 + kg * 16) ^ X);

  auto stage = [&](int p) {
#pragma unroll
    for (int i = 0; i < 4; i++)
      gload16(asrc[i], (char*)&As[p][0] + i * 4096 + wave * 1024);
#pragma unroll
    for (int i = 0; i < 4; i++)
      gload16(bsrc[i], (char*)&Bs[p][0] + i * 4096 + wave * 1024);
#pragma unroll
    for (int i = 0; i < 4; i++) { asrc[i] += 64; bsrc[i] += 64; }
  };
  auto compute = [&](int p) {
    const char* Ab = (const char*)&As[p][0];
    const char* Bb = (const char*)&Bs[p][0];
#pragma unroll
    for (int kk = 0; kk < 2; kk++) {
      int bA = kk ? bA1 : bA0;
      int bB = kk ? bB1 : bB0;
      bf16x8 af[4], bfr[4];
#pragma unroll
      for (int mi = 0; mi < 4; mi++)
        af[mi] = *(const bf16x8*)(Ab + bA + mi * 2048);
#pragma unroll
      for (int ni = 0; ni < 4; ni++)
        bfr[ni] = *(const bf16x8*)(Bb + bB + ni * 2048);
#pragma unroll
      for (int mi = 0; mi < 4; mi++)
#pragma unroll
        for (int ni = 0; ni < 4; ni++)
          acc[mi][ni] = __builtin_amdgcn_mfma_f32_16x16x32_bf16(af[mi], bfr[ni], acc[mi][ni], 0, 0, 0);
    }
  };

  stage(0);
  stage(1);
  for (int ks = 0; ks < 31; ks++) {
    WAIT_VM8();
    BARRIER();
    compute(ks & 1);
    BARRIER();
    if (ks < 30) stage(ks & 1);
  }
  WAIT_VM0();
  BARRIER();
  compute(1);

  int tok[4][4];
#pragma unroll
  for (int mi = 0; mi < 4; mi++)
#pragma unroll
    for (int j = 0; j < 4; j++)
      tok[mi][j] = perm[row0 + wm + mi * 16 + kg * 4 + j];
#pragma unroll
  for (int mi = 0; mi < 4; mi++)
#pragma unroll
    for (int ni = 0; ni < 4; ni++)
#pragma unroll
      for (int j = 0; j < 4; j++) {
        if (tok[mi][j] >= 0) {
          int col = nt * 128 + wn + ni * 16 + r;
          atomicAdd(out + (size_t)tok[mi][j] * 1024 + col, acc[mi][ni][j]);
        }
      }
}

extern "C" void kernel_launch(void* const* d_in, const int* in_sizes, int n_in,
                              void* d_out, int out_size, void* d_ws, size_t ws_size,
                              hipStream_t stream) {
  const float* x  = (const float*)d_in[0];
  const float* rw = (const float*)d_in[1];
  const float* w1 = (const float*)d_in[2];
  const float* w2 = (const float*)d_in[3];
  float* out = (float*)d_out;
  char* ws = (char*)d_ws;

  size_t off = 0;
  auto take = [&](size_t n) { char* p = ws + off; off += (n + 255) & ~255ull; return p; };
  u16* w1t   = (u16*)take(8ull * 4096 * 1024 * 2);
  u16* w2t   = (u16*)take(8ull * 4096 * 1024 * 2);
  u16* xb    = (u16*)take((size_t)T_TOKENS * HID * 2);
  u16* hbuf  = (u16*)take((size_t)MAXROWS * FFN_ * 2);
  int* sel   = (int*)take(T_TOKENS * 2 * 4);
  float* gsel = (float*)take(T_TOKENS * 2 * 4);
  int* perm  = (int*)take(MAXROWS * 4);
  float* grow = (float*)take(MAXROWS * 4);
  int* tmap  = (int*)take(MAXTILES * 4);
  int* counts = (int*)take(NE * 4);
  int* cursor = (int*)take(NE * 4);
  int* done  = (int*)take(4);
  u16* zp    = (u16*)take(4096);

  hipMemsetAsync(out, 0, (size_t)T_TOKENS * HID * 4, stream);

  transpose_weights<<<dim3(16384), 256, 0, stream>>>(w1, w1t, w2, w2t);
  router_kernel<<<dim3(T_TOKENS / 4), 256, 0, stream>>>(x, rw, sel, gsel, xb, counts, done, zp);
  hist_fill_kernel<<<dim3(MAXROWS / 256), 256, 0, stream>>>(sel, counts, perm, grow, done, cursor, tmap);
  scatter_kernel<<<dim3(T_TOKENS * 2 / 256), 256, 0, stream>>>(sel, gsel, cursor, perm, grow);
  gemm1_kernel<<<dim3(72 * 32), 256, 0, stream>>>(xb, w1t, perm, grow, tmap, hbuf, zp);
  gemm2_kernel<<<dim3(72 * 8 * KSPLIT2), 256, 0, stream>>>(hbuf, w2t, perm, tmap, out);
}